// Round 8
// baseline (326.754 us; speedup 1.0000x reference)
//
#include <hip/hip_runtime.h>
#include <math.h>

// Problem constants: B=16, N=128, h=256, goal_dim=64, obs_dim=128, local=64, skills=16
// ROUND 8 = ROUND 6 (best, 41.8us) + DIAGNOSTIC x2 repeat of attn phases.
// The repeat is idempotent (recomputes identical values into the same places);
// dur_us - 41.8 gives the attn-body duration, and if the dispatch exceeds the
// harness fill kernels (~40us) we finally get per-kernel counters in top-5.

typedef float f32x4 __attribute__((ext_vector_type(4)));
typedef short s16x8 __attribute__((ext_vector_type(8)));

// ---- workspace layout (float offsets) ----
#define WOBF_OFF  0        // bf16 [256][256] (row-major, = original Wo layout)
#define QBF_OFF   32768    // bf16 [2048][256] row-major
#define KBF_OFF   294912   // bf16 [2048][256] row-major
#define VTBF_OFF  557056   // bf16 [16][256][128]  (V transposed per batch)

// ---- output layout (float offsets, tuple return order) ----
#define LOGIT_OFF 0        // [16][128][16]
#define MASK_OFF  32768    // [16][128][128]
#define ATTN_OFF  294912   // [16][128][128]
#define OUT_OFF   557056   // [16][128][256]

static __device__ __forceinline__ unsigned short f2bf(float x) {
  unsigned int u = __float_as_uint(x);
  u = (u + 0x7fffu + ((u >> 16) & 1u)) >> 16;   // RNE
  return (unsigned short)u;
}
static __device__ __forceinline__ float bf2f(unsigned short h) {
  return __uint_as_float(((unsigned int)h) << 16);
}

// split 8 consecutive f32 (16B-aligned) into hi/lo bf16 MFMA fragments
static __device__ __forceinline__ void split8(const float* __restrict__ p,
                                              s16x8* hi, s16x8* lo) {
  float4 x0 = *(const float4*)p;
  float4 x1 = *(const float4*)(p + 4);
  float xs[8] = {x0.x, x0.y, x0.z, x0.w, x1.x, x1.y, x1.z, x1.w};
#pragma unroll
  for (int j = 0; j < 8; j++) {
    unsigned short h = f2bf(xs[j]);
    (*hi)[j] = (short)h;
    (*lo)[j] = (short)f2bf(xs[j] - bf2f(h));
  }
}

// 256 blocks x 512 threads. block = (16-row window = bid>>1, col-half = bid&1).
__global__ __launch_bounds__(512) void proj_k(
    const float* __restrict__ goals, const float* __restrict__ agents,
    const float* __restrict__ Wq, const float* __restrict__ bq,
    const float* __restrict__ Wk, const float* __restrict__ bk,
    const float* __restrict__ Wv, const float* __restrict__ bv,
    const float* __restrict__ Wo, float* __restrict__ ws) {
  unsigned short* qbf  = (unsigned short*)(ws + QBF_OFF);
  unsigned short* kbf  = (unsigned short*)(ws + KBF_OFF);
  unsigned short* vtbf = (unsigned short*)(ws + VTBF_OFF);
  unsigned short* wobf = (unsigned short*)(ws + WOBF_OFF);

  __shared__ __align__(16) float xg[16 * 68];    // goal rows, stride 68
  __shared__ __align__(16) float xa[16 * 132];   // agent rows, stride 132

  int t = threadIdx.x;
  int bid = blockIdx.x;
  int r0 = (bid >> 1) * 16;
  int colbase = (bid & 1) * 128;
  int bb = r0 >> 7;

  for (int i = t; i < 1024; i += 512) xg[(i >> 6) * 68 + (i & 63)] = goals[(size_t)r0 * 64 + i];
  for (int i = t; i < 2048; i += 512) xa[(i >> 7) * 132 + (i & 127)] = agents[(size_t)r0 * 128 + i];
  if (t < 256) {                                  // Wo -> bf16 (256/block x 256 blocks)
    int j = bid * 256 + t;
    wobf[j] = f2bf(Wo[j]);
  }
  __syncthreads();

  int w = t >> 6, l = t & 63, lr = l & 15, lc = l >> 4;
  int oc = colbase + w * 16 + lr;                 // output col = weight row

  // ---- Q: k=64 (2 ksteps x 3 MFMA) ----
  {
    f32x4 acc = {0.f, 0.f, 0.f, 0.f};
#pragma unroll
    for (int kk = 0; kk < 2; kk++) {
      s16x8 ahi, alo, bhi, blo;
      split8(&xg[lr * 68 + kk * 32 + lc * 8], &ahi, &alo);
      split8(&Wq[(size_t)oc * 64 + kk * 32 + lc * 8], &bhi, &blo);
      acc = __builtin_amdgcn_mfma_f32_16x16x32_bf16(ahi, bhi, acc, 0, 0, 0);
      acc = __builtin_amdgcn_mfma_f32_16x16x32_bf16(alo, bhi, acc, 0, 0, 0);
      acc = __builtin_amdgcn_mfma_f32_16x16x32_bf16(ahi, blo, acc, 0, 0, 0);
    }
    float bqv = bq[oc];
#pragma unroll
    for (int q = 0; q < 4; q++)
      qbf[(size_t)(r0 + 4 * lc + q) * 256 + oc] = f2bf(acc[q] + bqv);
  }
  // ---- K: k=128 (4 ksteps x 3 MFMA) ----
  {
    f32x4 acc = {0.f, 0.f, 0.f, 0.f};
#pragma unroll
    for (int kk = 0; kk < 4; kk++) {
      s16x8 ahi, alo, bhi, blo;
      split8(&xa[lr * 132 + kk * 32 + lc * 8], &ahi, &alo);
      split8(&Wk[(size_t)oc * 128 + kk * 32 + lc * 8], &bhi, &blo);
      acc = __builtin_amdgcn_mfma_f32_16x16x32_bf16(ahi, bhi, acc, 0, 0, 0);
      acc = __builtin_amdgcn_mfma_f32_16x16x32_bf16(alo, bhi, acc, 0, 0, 0);
      acc = __builtin_amdgcn_mfma_f32_16x16x32_bf16(ahi, blo, acc, 0, 0, 0);
    }
    float bkv = bk[oc];
#pragma unroll
    for (int q = 0; q < 4; q++)
      kbf[(size_t)(r0 + 4 * lc + q) * 256 + oc] = f2bf(acc[q] + bkv);
  }
  // ---- V: k=128, store transposed [b][h][m] ----
  {
    f32x4 acc = {0.f, 0.f, 0.f, 0.f};
#pragma unroll
    for (int kk = 0; kk < 4; kk++) {
      s16x8 ahi, alo, bhi, blo;
      split8(&xa[lr * 132 + kk * 32 + lc * 8], &ahi, &alo);
      split8(&Wv[(size_t)oc * 128 + kk * 32 + lc * 8], &bhi, &blo);
      acc = __builtin_amdgcn_mfma_f32_16x16x32_bf16(ahi, bhi, acc, 0, 0, 0);
      acc = __builtin_amdgcn_mfma_f32_16x16x32_bf16(alo, bhi, acc, 0, 0, 0);
      acc = __builtin_amdgcn_mfma_f32_16x16x32_bf16(ahi, blo, acc, 0, 0, 0);
    }
    float bvv = bv[oc];
    int m0 = r0 & 127;
#pragma unroll
    for (int q = 0; q < 4; q++)
      vtbf[(size_t)(bb * 256 + oc) * 128 + m0 + 4 * lc + q] = f2bf(acc[q] + bvv);
  }
}

// 512 blocks x 512 threads. block = (b = bid&15, 4-row tile n0 = (bid>>4)*4).
// DIAGNOSTIC: attn body repeated x2 (idempotent).
__global__ __launch_bounds__(512, 4) void attn_k(
    const float* __restrict__ goals, const float* __restrict__ agents_local,
    const float* __restrict__ u1, const float* __restrict__ u2,
    const float* __restrict__ bo, const float* __restrict__ Wsm,
    const float* __restrict__ bs, const float* __restrict__ ws,
    float* __restrict__ out) {
  const unsigned short* Qbf  = (const unsigned short*)(ws + QBF_OFF);
  const unsigned short* Kbf  = (const unsigned short*)(ws + KBF_OFF);
  const unsigned short* VTbf = (const unsigned short*)(ws + VTBF_OFF);
  const unsigned short* Wobf = (const unsigned short*)(ws + WOBF_OFF);
  float* o_logit = out + LOGIT_OFF;
  float* o_mask  = out + MASK_OFF;
  float* o_attn  = out + ATTN_OFF;
  float* o_out   = out + OUT_OFF;

  int bid = blockIdx.x;
  int b  = bid & 15;
  int n0 = (bid >> 4) << 2;    // 0..124 step 4
  int rtile = n0 & 0x70;       // 16-row MFMA window base
  int soff  = n0 & 12;         // our 4 rows within the window
  int t = threadIdx.x;
  int w = t >> 6, l = t & 63, lr = l & 15, lc = l >> 4;

  __shared__ __align__(16) float Sp[4][132];             // our 4 logit rows
  __shared__ __align__(16) unsigned short Wb[16 * 136];  // attn*mask (A of PV)
  __shared__ __align__(16) unsigned short Ib[16 * 264];  // info bf16 (A of O)
  __shared__ __align__(16) float outb[4 * 260];          // out rows (skill in)
  __shared__ float redmax[4][2], redsum[4][2];

  // ---- prefetch ----
  int pm = t & 127, prl = t >> 7;
  int prow = b * 128 + n0 + prl;
  float uu1 = u1[(size_t)prow * 128 + pm];
  float uu2 = u2[(size_t)prow * 128 + pm];
  float bov0 = bo[w * 16 + lr];
  float bov1 = bo[(w + 8) * 16 + lr];

#pragma unroll 1
  for (int rep = 0; rep < 2; ++rep) {
    __syncthreads();

    // ---- phase L: logits MFMA. wave w -> m-tile w, k=256 (8 MFMAs) ----
    {
      const s16x8* ap = (const s16x8*)(Qbf + (size_t)(b * 128 + rtile + lr) * 256);
      const s16x8* bp = (const s16x8*)(Kbf + (size_t)(b * 128 + w * 16 + lr) * 256);
      f32x4 acc = {0.f, 0.f, 0.f, 0.f};
#pragma unroll
      for (int kk = 0; kk < 8; kk++)
        acc = __builtin_amdgcn_mfma_f32_16x16x32_bf16(ap[kk * 4 + lc], bp[kk * 4 + lc], acc, 0, 0, 0);
      if (lc == (soff >> 2)) {
#pragma unroll
        for (int q = 0; q < 4; q++) Sp[q][w * 16 + lr] = acc[q] * 0.0625f;
      }
      for (int i = t; i < 1088; i += 512) ((unsigned int*)Wb)[i] = 0u;
    }
    __syncthreads();

    // ---- phase S: gumbel-sigmoid mask + scores + softmax ----
    {
      int half = (t >> 6) & 1;
      float lg = Sp[prl][pm];
      float g1 = -__logf(-__logf(uu1 + 1e-20f) + 1e-20f);
      float g2 = -__logf(-__logf(uu2 + 1e-20f) + 1e-20f);
      float z = lg + g1 - g2;                       // TAU = 1
      float mkv = 1.0f / (1.0f + __expf(-z));
      o_mask[(size_t)prow * 128 + pm] = mkv;
      float sc = lg + __logf(mkv + 1e-8f);
      float v = sc;
#pragma unroll
      for (int off = 32; off >= 1; off >>= 1) v = fmaxf(v, __shfl_xor(v, off));
      if (l == 0) redmax[prl][half] = v;
      __syncthreads();
      float rmax = fmaxf(redmax[prl][0], redmax[prl][1]);
      float e = __expf(sc - rmax);
      float s = e;
#pragma unroll
      for (int off = 32; off >= 1; off >>= 1) s += __shfl_xor(s, off);
      if (l == 0) redsum[prl][half] = s;
      __syncthreads();
      float rsum = redsum[prl][0] + redsum[prl][1];
      float attn = e / rsum;
      o_attn[(size_t)prow * 128 + pm] = attn;
      Wb[(soff + prl) * 136 + pm] = f2bf(attn * mkv);
    }
    __syncthreads();

    // ---- phase PV: info = W x V. wave w -> h-tiles w*16, (w+8)*16 ----
    {
#pragma unroll
      for (int hs = 0; hs < 2; hs++) {
        int h0 = (w + 8 * hs) * 16;
        f32x4 acc = {0.f, 0.f, 0.f, 0.f};
#pragma unroll
        for (int kk = 0; kk < 4; kk++) {
          s16x8 a = *(const s16x8*)(Wb + lr * 136 + kk * 32 + lc * 8);
          s16x8 bfr = *(const s16x8*)(VTbf + (size_t)(b * 256 + h0 + lr) * 128 + kk * 32 + lc * 8);
          acc = __builtin_amdgcn_mfma_f32_16x16x32_bf16(a, bfr, acc, 0, 0, 0);
        }
#pragma unroll
        for (int q = 0; q < 4; q++) Ib[(4 * lc + q) * 264 + h0 + lr] = f2bf(acc[q]);
      }
    }
    __syncthreads();

    // ---- phase O: out = info x Wo^T. wave w -> g-tiles w*16, (w+8)*16 ----
    {
#pragma unroll
      for (int gs = 0; gs < 2; gs++) {
        int g0 = (w + 8 * gs) * 16;
        f32x4 acc = {0.f, 0.f, 0.f, 0.f};
#pragma unroll
        for (int kk = 0; kk < 8; kk++) {
          s16x8 a = *(const s16x8*)(Ib + lr * 264 + kk * 32 + lc * 8);
          s16x8 bfr = *(const s16x8*)(Wobf + (size_t)(g0 + lr) * 256 + kk * 32 + lc * 8);
          acc = __builtin_amdgcn_mfma_f32_16x16x32_bf16(a, bfr, acc, 0, 0, 0);
        }
        float bov = gs ? bov1 : bov0;
        if (lc == (soff >> 2)) {                    // rows we own
#pragma unroll
          for (int q = 0; q < 4; q++) {
            float val = acc[q] + bov;
            o_out[(size_t)(b * 128 + n0 + q) * 256 + g0 + lr] = val;
            outb[q * 260 + g0 + lr] = val;
          }
        }
      }
    }
    __syncthreads();

    // ---- phase K: skill logits. t = (rloc<<7)|(s<<3)|p, 8-way split-K ----
    {
      int rloc = t >> 7, s = (t >> 3) & 15, p = t & 7;
      int row = b * 128 + n0 + rloc;
      const float4* Ws4 = (const float4*)(Wsm + s * 384);
      const float4* lp4 = (const float4*)(agents_local + (size_t)row * 64);
      const float4* gp4 = (const float4*)(goals + (size_t)row * 64);
      float acc = 0.f;
#pragma unroll
      for (int i = 0; i < 12; i++) {
        int cc = p * 48 + i * 4;
        float4 c4;
        if (cc < 64)       c4 = lp4[cc >> 2];
        else if (cc < 128) c4 = gp4[(cc - 64) >> 2];
        else               c4 = *(const float4*)&outb[rloc * 260 + (cc - 128)];
        float4 w4 = Ws4[cc >> 2];
        acc = fmaf(w4.x, c4.x, fmaf(w4.y, c4.y, fmaf(w4.z, c4.z, fmaf(w4.w, c4.w, acc))));
      }
      acc += __shfl_xor(acc, 1);
      acc += __shfl_xor(acc, 2);
      acc += __shfl_xor(acc, 4);
      if (p == 0) o_logit[row * 16 + s] = acc + bs[s];
    }
  }
}

extern "C" void kernel_launch(void* const* d_in, const int* in_sizes, int n_in,
                              void* d_out, int out_size, void* d_ws, size_t ws_size,
                              hipStream_t stream) {
  const float* goals        = (const float*)d_in[0];
  const float* agents       = (const float*)d_in[1];
  const float* agents_local = (const float*)d_in[2];
  const float* u1           = (const float*)d_in[3];
  const float* u2           = (const float*)d_in[4];
  const float* Wq = (const float*)d_in[5];
  const float* bq = (const float*)d_in[6];
  const float* Wk = (const float*)d_in[7];
  const float* bk = (const float*)d_in[8];
  const float* Wv = (const float*)d_in[9];
  const float* bv = (const float*)d_in[10];
  const float* Wo = (const float*)d_in[11];
  const float* bo = (const float*)d_in[12];
  const float* Wsm = (const float*)d_in[13];
  const float* bs  = (const float*)d_in[14];
  float* out = (float*)d_out;
  float* ws  = (float*)d_ws;

  proj_k<<<256, 512, 0, stream>>>(goals, agents, Wq, bq, Wk, bk, Wv, bv, Wo, ws);
  attn_k<<<512, 512, 0, stream>>>(goals, agents_local, u1, u2, bo, Wsm, bs, ws, out);
}

// Round 9
// 34.946 us; speedup vs baseline: 9.3504x; 9.3504x over previous
//
#include <hip/hip_runtime.h>
#include <math.h>

// Problem constants: B=16, N=128, h=256, goal_dim=64, obs_dim=128, local=64, skills=16

typedef float f32x4 __attribute__((ext_vector_type(4)));
typedef short s16x8 __attribute__((ext_vector_type(8)));

// ---- workspace layout (float offsets) ----
#define WOBF_OFF  0        // bf16 [256][256] (row-major, = original Wo layout)
#define QBF_OFF   32768    // bf16 [2048][256] row-major
#define KBF_OFF   294912   // bf16 [2048][256] row-major
#define VTBF_OFF  557056   // bf16 [16][256][128]  (V transposed per batch)

// ---- output layout (float offsets, tuple return order) ----
#define LOGIT_OFF 0        // [16][128][16]
#define MASK_OFF  32768    // [16][128][128]
#define ATTN_OFF  294912   // [16][128][128]
#define OUT_OFF   557056   // [16][128][256]

static __device__ __forceinline__ unsigned short f2bf(float x) {
  unsigned int u = __float_as_uint(x);
  u = (u + 0x7fffu + ((u >> 16) & 1u)) >> 16;   // RNE
  return (unsigned short)u;
}
static __device__ __forceinline__ float bf2f(unsigned short h) {
  return __uint_as_float(((unsigned int)h) << 16);
}

// split 8 consecutive f32 (16B-aligned) into hi/lo bf16 MFMA fragments
static __device__ __forceinline__ void split8(const float* __restrict__ p,
                                              s16x8* hi, s16x8* lo) {
  float4 x0 = *(const float4*)p;
  float4 x1 = *(const float4*)(p + 4);
  float xs[8] = {x0.x, x0.y, x0.z, x0.w, x1.x, x1.y, x1.z, x1.w};
#pragma unroll
  for (int j = 0; j < 8; j++) {
    unsigned short h = f2bf(xs[j]);
    (*hi)[j] = (short)h;
    (*lo)[j] = (short)f2bf(xs[j] - bf2f(h));
  }
}

// ---------------- proj_k: UNCHANGED from Round 6 (baseline for subtraction) ----
__global__ __launch_bounds__(512) void proj_k(
    const float* __restrict__ goals, const float* __restrict__ agents,
    const float* __restrict__ Wq, const float* __restrict__ bq,
    const float* __restrict__ Wk, const float* __restrict__ bk,
    const float* __restrict__ Wv, const float* __restrict__ bv,
    const float* __restrict__ Wo, float* __restrict__ ws) {
  unsigned short* qbf  = (unsigned short*)(ws + QBF_OFF);
  unsigned short* kbf  = (unsigned short*)(ws + KBF_OFF);
  unsigned short* vtbf = (unsigned short*)(ws + VTBF_OFF);
  unsigned short* wobf = (unsigned short*)(ws + WOBF_OFF);

  __shared__ __align__(16) float xg[16 * 68];
  __shared__ __align__(16) float xa[16 * 132];

  int t = threadIdx.x;
  int bid = blockIdx.x;
  int r0 = (bid >> 1) * 16;
  int colbase = (bid & 1) * 128;
  int bb = r0 >> 7;

  for (int i = t; i < 1024; i += 512) xg[(i >> 6) * 68 + (i & 63)] = goals[(size_t)r0 * 64 + i];
  for (int i = t; i < 2048; i += 512) xa[(i >> 7) * 132 + (i & 127)] = agents[(size_t)r0 * 128 + i];
  if (t < 256) {
    int j = bid * 256 + t;
    wobf[j] = f2bf(Wo[j]);
  }
  __syncthreads();

  int w = t >> 6, l = t & 63, lr = l & 15, lc = l >> 4;
  int oc = colbase + w * 16 + lr;

  {
    f32x4 acc = {0.f, 0.f, 0.f, 0.f};
#pragma unroll
    for (int kk = 0; kk < 2; kk++) {
      s16x8 ahi, alo, bhi, blo;
      split8(&xg[lr * 68 + kk * 32 + lc * 8], &ahi, &alo);
      split8(&Wq[(size_t)oc * 64 + kk * 32 + lc * 8], &bhi, &blo);
      acc = __builtin_amdgcn_mfma_f32_16x16x32_bf16(ahi, bhi, acc, 0, 0, 0);
      acc = __builtin_amdgcn_mfma_f32_16x16x32_bf16(alo, bhi, acc, 0, 0, 0);
      acc = __builtin_amdgcn_mfma_f32_16x16x32_bf16(ahi, blo, acc, 0, 0, 0);
    }
    float bqv = bq[oc];
#pragma unroll
    for (int q = 0; q < 4; q++)
      qbf[(size_t)(r0 + 4 * lc + q) * 256 + oc] = f2bf(acc[q] + bqv);
  }
  {
    f32x4 acc = {0.f, 0.f, 0.f, 0.f};
#pragma unroll
    for (int kk = 0; kk < 4; kk++) {
      s16x8 ahi, alo, bhi, blo;
      split8(&xa[lr * 132 + kk * 32 + lc * 8], &ahi, &alo);
      split8(&Wk[(size_t)oc * 128 + kk * 32 + lc * 8], &bhi, &blo);
      acc = __builtin_amdgcn_mfma_f32_16x16x32_bf16(ahi, bhi, acc, 0, 0, 0);
      acc = __builtin_amdgcn_mfma_f32_16x16x32_bf16(alo, bhi, acc, 0, 0, 0);
      acc = __builtin_amdgcn_mfma_f32_16x16x32_bf16(ahi, blo, acc, 0, 0, 0);
    }
    float bkv = bk[oc];
#pragma unroll
    for (int q = 0; q < 4; q++)
      kbf[(size_t)(r0 + 4 * lc + q) * 256 + oc] = f2bf(acc[q] + bkv);
  }
  {
    f32x4 acc = {0.f, 0.f, 0.f, 0.f};
#pragma unroll
    for (int kk = 0; kk < 4; kk++) {
      s16x8 ahi, alo, bhi, blo;
      split8(&xa[lr * 132 + kk * 32 + lc * 8], &ahi, &alo);
      split8(&Wv[(size_t)oc * 128 + kk * 32 + lc * 8], &bhi, &blo);
      acc = __builtin_amdgcn_mfma_f32_16x16x32_bf16(ahi, bhi, acc, 0, 0, 0);
      acc = __builtin_amdgcn_mfma_f32_16x16x32_bf16(alo, bhi, acc, 0, 0, 0);
      acc = __builtin_amdgcn_mfma_f32_16x16x32_bf16(ahi, blo, acc, 0, 0, 0);
    }
    float bvv = bv[oc];
    int m0 = r0 & 127;
#pragma unroll
    for (int q = 0; q < 4; q++)
      vtbf[(size_t)(bb * 256 + oc) * 128 + m0 + 4 * lc + q] = f2bf(acc[q] + bvv);
  }
}

// ---------------- attn_k: 256 blocks x 512 thr, 8-row tiles, XCD-local ----
// bid -> xcd = bid&7, idx = bid>>3; b = 2*xcd + (idx&1); n0 = (idx>>1)*8.
// Each XCD's blocks touch only 2 batches -> per-XCD L2 footprint ~0.5 MB.
__global__ __launch_bounds__(512) void attn_k(
    const float* __restrict__ goals, const float* __restrict__ agents_local,
    const float* __restrict__ u1, const float* __restrict__ u2,
    const float* __restrict__ bo, const float* __restrict__ Wsm,
    const float* __restrict__ bs, const float* __restrict__ ws,
    float* __restrict__ out) {
  const unsigned short* Qbf  = (const unsigned short*)(ws + QBF_OFF);
  const unsigned short* Kbf  = (const unsigned short*)(ws + KBF_OFF);
  const unsigned short* VTbf = (const unsigned short*)(ws + VTBF_OFF);
  const unsigned short* Wobf = (const unsigned short*)(ws + WOBF_OFF);
  float* o_logit = out + LOGIT_OFF;
  float* o_mask  = out + MASK_OFF;
  float* o_attn  = out + ATTN_OFF;
  float* o_out   = out + OUT_OFF;

  int bid = blockIdx.x;
  int xcd = bid & 7, idx = bid >> 3;
  int b  = 2 * xcd + (idx & 1);
  int n0 = (idx >> 1) << 3;            // 0..120 step 8
  int rtile = n0 & 0x70;               // 16-row MFMA window base
  int soff  = n0 & 8;                  // our 8 rows within the window
  int t = threadIdx.x;
  int w = t >> 6, l = t & 63, lr = l & 15, lc = l >> 4;

  __shared__ __align__(16) float Sp[8 * 132];            // our 8 logit rows
  __shared__ __align__(16) unsigned short Wb[16 * 136];  // attn*mask (A of PV)
  __shared__ __align__(16) unsigned short Ib[16 * 264];  // info bf16 (A of O)
  __shared__ __align__(16) float outb[8 * 260];          // out rows (skill in)
  __shared__ float redmax[8][2], redsum[8][2];

  // ---- prefetch u1/u2 (2 rows/thread) + bo (hidden under phase L) ----
  int pm = t & 127, r2 = t >> 7;       // r2 0..3 -> rows r2, r2+4
  int rowa = b * 128 + n0 + r2, rowb = rowa + 4;
  float uu1a = u1[(size_t)rowa * 128 + pm];
  float uu1b = u1[(size_t)rowb * 128 + pm];
  float uu2a = u2[(size_t)rowa * 128 + pm];
  float uu2b = u2[(size_t)rowb * 128 + pm];
  float bov0 = bo[w * 16 + lr];
  float bov1 = bo[(w + 8) * 16 + lr];

  // ---- phase L: logits MFMA. wave w -> m-tile w, k=256 (8 MFMAs) ----
  {
    const s16x8* ap = (const s16x8*)(Qbf + (size_t)(b * 128 + rtile + lr) * 256);
    const s16x8* bp = (const s16x8*)(Kbf + (size_t)(b * 128 + w * 16 + lr) * 256);
    f32x4 acc = {0.f, 0.f, 0.f, 0.f};
#pragma unroll
    for (int kk = 0; kk < 8; kk++)
      acc = __builtin_amdgcn_mfma_f32_16x16x32_bf16(ap[kk * 4 + lc], bp[kk * 4 + lc], acc, 0, 0, 0);
    if ((lc >> 1) == (soff >> 3)) {    // rows we own
#pragma unroll
      for (int q = 0; q < 4; q++) Sp[((4 * lc + q) & 7) * 132 + w * 16 + lr] = acc[q] * 0.0625f;
    }
    // zero the other-half rows of Wb (8 rows x 136 bf16 = 544 u32)
    if (t < 544) ((unsigned int*)(Wb + (soff ^ 8) * 136))[t] = 0u;
  }
  __syncthreads();

  // ---- phase S: gumbel-sigmoid mask + scores + softmax (2 rows/thread) ----
  {
    int half = (t >> 6) & 1;
    int ra = r2, rb = r2 + 4;
    float lga = Sp[ra * 132 + pm], lgb = Sp[rb * 132 + pm];
    float g1a = -__logf(-__logf(uu1a + 1e-20f) + 1e-20f);
    float g2a = -__logf(-__logf(uu2a + 1e-20f) + 1e-20f);
    float g1b = -__logf(-__logf(uu1b + 1e-20f) + 1e-20f);
    float g2b = -__logf(-__logf(uu2b + 1e-20f) + 1e-20f);
    float mka = 1.0f / (1.0f + __expf(-(lga + g1a - g2a)));
    float mkb = 1.0f / (1.0f + __expf(-(lgb + g1b - g2b)));
    o_mask[(size_t)rowa * 128 + pm] = mka;
    o_mask[(size_t)rowb * 128 + pm] = mkb;
    float sca = lga + __logf(mka + 1e-8f);
    float scb = lgb + __logf(mkb + 1e-8f);
    float v0 = sca, v1 = scb;
#pragma unroll
    for (int off = 32; off >= 1; off >>= 1) {
      v0 = fmaxf(v0, __shfl_xor(v0, off));
      v1 = fmaxf(v1, __shfl_xor(v1, off));
    }
    if (l == 0) { redmax[ra][half] = v0; redmax[rb][half] = v1; }
    __syncthreads();
    float mxa = fmaxf(redmax[ra][0], redmax[ra][1]);
    float mxb = fmaxf(redmax[rb][0], redmax[rb][1]);
    float ea = __expf(sca - mxa), eb = __expf(scb - mxb);
    float s0 = ea, s1 = eb;
#pragma unroll
    for (int off = 32; off >= 1; off >>= 1) {
      s0 += __shfl_xor(s0, off);
      s1 += __shfl_xor(s1, off);
    }
    if (l == 0) { redsum[ra][half] = s0; redsum[rb][half] = s1; }
    __syncthreads();
    float sa = redsum[ra][0] + redsum[ra][1];
    float sb = redsum[rb][0] + redsum[rb][1];
    float ata = ea / sa, atb = eb / sb;
    o_attn[(size_t)rowa * 128 + pm] = ata;
    o_attn[(size_t)rowb * 128 + pm] = atb;
    Wb[(soff + ra) * 136 + pm] = f2bf(ata * mka);
    Wb[(soff + rb) * 136 + pm] = f2bf(atb * mkb);
  }
  __syncthreads();

  // ---- phase PV: info = W x V. wave w -> h-tiles w*16, (w+8)*16 ----
  {
#pragma unroll
    for (int hs = 0; hs < 2; hs++) {
      int h0 = (w + 8 * hs) * 16;
      f32x4 acc = {0.f, 0.f, 0.f, 0.f};
#pragma unroll
      for (int kk = 0; kk < 4; kk++) {
        s16x8 a = *(const s16x8*)(Wb + lr * 136 + kk * 32 + lc * 8);
        s16x8 bfr = *(const s16x8*)(VTbf + (size_t)(b * 256 + h0 + lr) * 128 + kk * 32 + lc * 8);
        acc = __builtin_amdgcn_mfma_f32_16x16x32_bf16(a, bfr, acc, 0, 0, 0);
      }
#pragma unroll
      for (int q = 0; q < 4; q++) Ib[(4 * lc + q) * 264 + h0 + lr] = f2bf(acc[q]);
    }
  }
  __syncthreads();

  // ---- phase O: out = info x Wo^T. wave w -> g-tiles w*16, (w+8)*16 ----
  {
#pragma unroll
    for (int gs = 0; gs < 2; gs++) {
      int g0 = (w + 8 * gs) * 16;
      f32x4 acc = {0.f, 0.f, 0.f, 0.f};
#pragma unroll
      for (int kk = 0; kk < 8; kk++) {
        s16x8 a = *(const s16x8*)(Ib + lr * 264 + kk * 32 + lc * 8);
        s16x8 bfr = *(const s16x8*)(Wobf + (size_t)(g0 + lr) * 256 + kk * 32 + lc * 8);
        acc = __builtin_amdgcn_mfma_f32_16x16x32_bf16(a, bfr, acc, 0, 0, 0);
      }
      float bov = gs ? bov1 : bov0;
      if ((lc >> 1) == (soff >> 3)) {   // rows we own
#pragma unroll
        for (int q = 0; q < 4; q++) {
          int rloc = (4 * lc + q) & 7;
          float val = acc[q] + bov;
          o_out[(size_t)(b * 128 + n0 + rloc) * 256 + g0 + lr] = val;
          outb[rloc * 260 + g0 + lr] = val;
        }
      }
    }
  }
  __syncthreads();

  // ---- phase K: skill logits. t = (rloc<<6)|(s<<2)|p, 4-way split-K ----
  {
    int rloc = t >> 6, s = (t >> 2) & 15, p = t & 3;
    int row = b * 128 + n0 + rloc;
    const float4* Ws4 = (const float4*)(Wsm + s * 384);
    const float4* lp4 = (const float4*)(agents_local + (size_t)row * 64);
    const float4* gp4 = (const float4*)(goals + (size_t)row * 64);
    float acc = 0.f;
#pragma unroll
    for (int i = 0; i < 24; i++) {
      int cc = p * 96 + i * 4;
      float4 c4;
      if (cc < 64)       c4 = lp4[cc >> 2];
      else if (cc < 128) c4 = gp4[(cc - 64) >> 2];
      else               c4 = *(const float4*)&outb[rloc * 260 + (cc - 128)];
      float4 w4 = Ws4[cc >> 2];
      acc = fmaf(w4.x, c4.x, fmaf(w4.y, c4.y, fmaf(w4.z, c4.z, fmaf(w4.w, c4.w, acc))));
    }
    acc += __shfl_xor(acc, 1);
    acc += __shfl_xor(acc, 2);
    if (p == 0) o_logit[row * 16 + s] = acc + bs[s];
  }
}

extern "C" void kernel_launch(void* const* d_in, const int* in_sizes, int n_in,
                              void* d_out, int out_size, void* d_ws, size_t ws_size,
                              hipStream_t stream) {
  const float* goals        = (const float*)d_in[0];
  const float* agents       = (const float*)d_in[1];
  const float* agents_local = (const float*)d_in[2];
  const float* u1           = (const float*)d_in[3];
  const float* u2           = (const float*)d_in[4];
  const float* Wq = (const float*)d_in[5];
  const float* bq = (const float*)d_in[6];
  const float* Wk = (const float*)d_in[7];
  const float* bk = (const float*)d_in[8];
  const float* Wv = (const float*)d_in[9];
  const float* bv = (const float*)d_in[10];
  const float* Wo = (const float*)d_in[11];
  const float* bo = (const float*)d_in[12];
  const float* Wsm = (const float*)d_in[13];
  const float* bs  = (const float*)d_in[14];
  float* out = (float*)d_out;
  float* ws  = (float*)d_ws;

  proj_k<<<256, 512, 0, stream>>>(goals, agents, Wq, bq, Wk, bk, Wv, bv, Wo, ws);
  attn_k<<<256, 512, 0, stream>>>(goals, agents_local, u1, u2, bo, Wsm, bs, ws, out);
}

// Round 10
// 33.878 us; speedup vs baseline: 9.6450x; 1.0315x over previous
//
#include <hip/hip_runtime.h>
#include <math.h>

// Problem constants: B=16, N=128, h=256, goal_dim=64, obs_dim=128, local=64, skills=16

typedef float f32x4 __attribute__((ext_vector_type(4)));
typedef short s16x8 __attribute__((ext_vector_type(8)));

// ---- workspace layout (float offsets) ----
#define WOBF_OFF  0        // bf16 [256][256] (row-major, = original Wo layout)
#define QBF_OFF   32768    // bf16 [2048][256] row-major
#define KBF_OFF   294912   // bf16 [2048][256] row-major
#define VTBF_OFF  557056   // bf16 [16][256][128]  (V transposed per batch)

// ---- output layout (float offsets, tuple return order) ----
#define LOGIT_OFF 0        // [16][128][16]
#define MASK_OFF  32768    // [16][128][128]
#define ATTN_OFF  294912   // [16][128][128]
#define OUT_OFF   557056   // [16][128][256]

static __device__ __forceinline__ unsigned short f2bf(float x) {
  unsigned int u = __float_as_uint(x);
  u = (u + 0x7fffu + ((u >> 16) & 1u)) >> 16;   // RNE
  return (unsigned short)u;
}
static __device__ __forceinline__ float bf2f(unsigned short h) {
  return __uint_as_float(((unsigned int)h) << 16);
}

// split 8 consecutive f32 (16B-aligned) into hi/lo bf16 MFMA fragments
static __device__ __forceinline__ void split8(const float* __restrict__ p,
                                              s16x8* hi, s16x8* lo) {
  float4 x0 = *(const float4*)p;
  float4 x1 = *(const float4*)(p + 4);
  float xs[8] = {x0.x, x0.y, x0.z, x0.w, x1.x, x1.y, x1.z, x1.w};
#pragma unroll
  for (int j = 0; j < 8; j++) {
    unsigned short h = f2bf(xs[j]);
    (*hi)[j] = (short)h;
    (*lo)[j] = (short)f2bf(xs[j] - bf2f(h));
  }
}

// ---------------- proj_k: R6 body, XCD-aligned block mapping ----------------
// Producer blocks for batch bb run on xcd = bb>>1 (same as attn's consumers),
// so Q/K/VT handoff stays in that XCD's L2.
__global__ __launch_bounds__(512) void proj_k(
    const float* __restrict__ goals, const float* __restrict__ agents,
    const float* __restrict__ Wq, const float* __restrict__ bq,
    const float* __restrict__ Wk, const float* __restrict__ bk,
    const float* __restrict__ Wv, const float* __restrict__ bv,
    const float* __restrict__ Wo, float* __restrict__ ws) {
  unsigned short* qbf  = (unsigned short*)(ws + QBF_OFF);
  unsigned short* kbf  = (unsigned short*)(ws + KBF_OFF);
  unsigned short* vtbf = (unsigned short*)(ws + VTBF_OFF);
  unsigned short* wobf = (unsigned short*)(ws + WOBF_OFF);

  __shared__ __align__(16) float xg[16 * 68];
  __shared__ __align__(16) float xa[16 * 132];

  int t = threadIdx.x;
  int bid = blockIdx.x;
  // XCD-aligned decode: xcd = bid&7 (dispatch round-robin heuristic)
  int xcd = bid & 7, j = bid >> 3;
  int bb = 2 * xcd + (j & 1);
  int sub = j >> 1;                 // 0..15 = (row-window, col-half)
  int r0 = bb * 128 + (sub >> 1) * 16;
  int colbase = (sub & 1) * 128;

  for (int i = t; i < 1024; i += 512) xg[(i >> 6) * 68 + (i & 63)] = goals[(size_t)r0 * 64 + i];
  for (int i = t; i < 2048; i += 512) xa[(i >> 7) * 132 + (i & 127)] = agents[(size_t)r0 * 128 + i];
  if (t < 256) {
    int jj = bid * 256 + t;
    wobf[jj] = f2bf(Wo[jj]);
  }
  __syncthreads();

  int w = t >> 6, l = t & 63, lr = l & 15, lc = l >> 4;
  int oc = colbase + w * 16 + lr;

  {
    f32x4 acc = {0.f, 0.f, 0.f, 0.f};
#pragma unroll
    for (int kk = 0; kk < 2; kk++) {
      s16x8 ahi, alo, bhi, blo;
      split8(&xg[lr * 68 + kk * 32 + lc * 8], &ahi, &alo);
      split8(&Wq[(size_t)oc * 64 + kk * 32 + lc * 8], &bhi, &blo);
      acc = __builtin_amdgcn_mfma_f32_16x16x32_bf16(ahi, bhi, acc, 0, 0, 0);
      acc = __builtin_amdgcn_mfma_f32_16x16x32_bf16(alo, bhi, acc, 0, 0, 0);
      acc = __builtin_amdgcn_mfma_f32_16x16x32_bf16(ahi, blo, acc, 0, 0, 0);
    }
    float bqv = bq[oc];
#pragma unroll
    for (int q = 0; q < 4; q++)
      qbf[(size_t)(r0 + 4 * lc + q) * 256 + oc] = f2bf(acc[q] + bqv);
  }
  {
    f32x4 acc = {0.f, 0.f, 0.f, 0.f};
#pragma unroll
    for (int kk = 0; kk < 4; kk++) {
      s16x8 ahi, alo, bhi, blo;
      split8(&xa[lr * 132 + kk * 32 + lc * 8], &ahi, &alo);
      split8(&Wk[(size_t)oc * 128 + kk * 32 + lc * 8], &bhi, &blo);
      acc = __builtin_amdgcn_mfma_f32_16x16x32_bf16(ahi, bhi, acc, 0, 0, 0);
      acc = __builtin_amdgcn_mfma_f32_16x16x32_bf16(alo, bhi, acc, 0, 0, 0);
      acc = __builtin_amdgcn_mfma_f32_16x16x32_bf16(ahi, blo, acc, 0, 0, 0);
    }
    float bkv = bk[oc];
#pragma unroll
    for (int q = 0; q < 4; q++)
      kbf[(size_t)(r0 + 4 * lc + q) * 256 + oc] = f2bf(acc[q] + bkv);
  }
  {
    f32x4 acc = {0.f, 0.f, 0.f, 0.f};
#pragma unroll
    for (int kk = 0; kk < 4; kk++) {
      s16x8 ahi, alo, bhi, blo;
      split8(&xa[lr * 132 + kk * 32 + lc * 8], &ahi, &alo);
      split8(&Wv[(size_t)oc * 128 + kk * 32 + lc * 8], &bhi, &blo);
      acc = __builtin_amdgcn_mfma_f32_16x16x32_bf16(ahi, bhi, acc, 0, 0, 0);
      acc = __builtin_amdgcn_mfma_f32_16x16x32_bf16(alo, bhi, acc, 0, 0, 0);
      acc = __builtin_amdgcn_mfma_f32_16x16x32_bf16(ahi, blo, acc, 0, 0, 0);
    }
    float bvv = bv[oc];
    int m0 = r0 & 127;
#pragma unroll
    for (int q = 0; q < 4; q++)
      vtbf[(size_t)(bb * 256 + oc) * 128 + m0 + 4 * lc + q] = f2bf(acc[q] + bvv);
  }
}

// ---------------- attn_k: 256 blocks x 1024 threads, 8-row tiles, XCD-local --
// 16 waves/block (4 waves/SIMD): logits k-split, 1 (row,m)/thread softmax,
// one 16-wide tile per wave in PV and O.
__global__ __launch_bounds__(1024) void attn_k(
    const float* __restrict__ goals, const float* __restrict__ agents_local,
    const float* __restrict__ u1, const float* __restrict__ u2,
    const float* __restrict__ bo, const float* __restrict__ Wsm,
    const float* __restrict__ bs, const float* __restrict__ ws,
    float* __restrict__ out) {
  const unsigned short* Qbf  = (const unsigned short*)(ws + QBF_OFF);
  const unsigned short* Kbf  = (const unsigned short*)(ws + KBF_OFF);
  const unsigned short* VTbf = (const unsigned short*)(ws + VTBF_OFF);
  const unsigned short* Wobf = (const unsigned short*)(ws + WOBF_OFF);
  float* o_logit = out + LOGIT_OFF;
  float* o_mask  = out + MASK_OFF;
  float* o_attn  = out + ATTN_OFF;
  float* o_out   = out + OUT_OFF;

  int bid = blockIdx.x;
  int xcd = bid & 7, idx = bid >> 3;
  int b  = 2 * xcd + (idx & 1);
  int n0 = (idx >> 1) << 3;            // 0..120 step 8
  int rtile = n0 & 0x70;               // 16-row MFMA window base
  int soff  = n0 & 8;                  // our 8 rows within the window
  int t = threadIdx.x;
  int w = t >> 6, l = t & 63, lr = l & 15, lc = l >> 4;

  __shared__ __align__(16) float Spp[2][8][132];         // logits k-half partials
  __shared__ __align__(16) unsigned short Wb[16 * 136];  // attn*mask (A of PV)
  __shared__ __align__(16) unsigned short Ib[16 * 264];  // info bf16 (A of O)
  __shared__ __align__(16) float outb[8 * 260];          // out rows (skill in)
  __shared__ float redmax[8][2], redsum[8][2];

  // ---- prefetch u1/u2 (1 row/thread) + bo (hidden under phase L) ----
  int pm = t & 127, prl = t >> 7;      // row prl (0..7), col pm
  int prow = b * 128 + n0 + prl;
  float uu1 = u1[(size_t)prow * 128 + pm];
  float uu2 = u2[(size_t)prow * 128 + pm];
  float bov = bo[w * 16 + lr];

  // ---- phase L: logits MFMA. wave w: m-tile = w&7, k-half = w>>3 (4 MFMAs) --
  {
    int mt = w & 7, kh = w >> 3;
    const s16x8* ap = (const s16x8*)(Qbf + (size_t)(b * 128 + rtile + lr) * 256 + kh * 128);
    const s16x8* bp = (const s16x8*)(Kbf + (size_t)(b * 128 + mt * 16 + lr) * 256 + kh * 128);
    f32x4 acc = {0.f, 0.f, 0.f, 0.f};
#pragma unroll
    for (int kk = 0; kk < 4; kk++)
      acc = __builtin_amdgcn_mfma_f32_16x16x32_bf16(ap[kk * 4 + lc], bp[kk * 4 + lc], acc, 0, 0, 0);
    if ((lc >> 1) == (soff >> 3)) {    // rows we own
#pragma unroll
      for (int q = 0; q < 4; q++) Spp[kh][(4 * lc + q) & 7][mt * 16 + lr] = acc[q];
    }
    // zero the other-half rows of Wb (8 rows x 136 bf16 = 544 u32)
    if (t < 544) ((unsigned int*)(Wb + (soff ^ 8) * 136))[t] = 0u;
  }
  __syncthreads();

  // ---- phase S: gumbel-sigmoid mask + scores + softmax (1 (row,m)/thread) --
  {
    int half = (t >> 6) & 1;
    float lg = (Spp[0][prl][pm] + Spp[1][prl][pm]) * 0.0625f;
    float g1 = -__logf(-__logf(uu1 + 1e-20f) + 1e-20f);
    float g2 = -__logf(-__logf(uu2 + 1e-20f) + 1e-20f);
    float mkv = 1.0f / (1.0f + __expf(-(lg + g1 - g2)));   // TAU = 1
    o_mask[(size_t)prow * 128 + pm] = mkv;
    float sc = lg + __logf(mkv + 1e-8f);
    float v = sc;
#pragma unroll
    for (int off = 32; off >= 1; off >>= 1) v = fmaxf(v, __shfl_xor(v, off));
    if (l == 0) redmax[prl][half] = v;
    __syncthreads();
    float rmax = fmaxf(redmax[prl][0], redmax[prl][1]);
    float e = __expf(sc - rmax);
    float s = e;
#pragma unroll
    for (int off = 32; off >= 1; off >>= 1) s += __shfl_xor(s, off);
    if (l == 0) redsum[prl][half] = s;
    __syncthreads();
    float rsum = redsum[prl][0] + redsum[prl][1];
    float attn = e / rsum;
    o_attn[(size_t)prow * 128 + pm] = attn;
    Wb[(soff + prl) * 136 + pm] = f2bf(attn * mkv);
  }
  __syncthreads();

  // ---- phase PV: info = W x V. wave w -> h-tile h0 = w*16 (4 MFMAs) ----
  {
    int h0 = w * 16;
    f32x4 acc = {0.f, 0.f, 0.f, 0.f};
#pragma unroll
    for (int kk = 0; kk < 4; kk++) {
      s16x8 a = *(const s16x8*)(Wb + lr * 136 + kk * 32 + lc * 8);
      s16x8 bfr = *(const s16x8*)(VTbf + (size_t)(b * 256 + h0 + lr) * 128 + kk * 32 + lc * 8);
      acc = __builtin_amdgcn_mfma_f32_16x16x32_bf16(a, bfr, acc, 0, 0, 0);
    }
#pragma unroll
    for (int q = 0; q < 4; q++) Ib[(4 * lc + q) * 264 + h0 + lr] = f2bf(acc[q]);
  }
  __syncthreads();

  // ---- phase O: out = info x Wo^T. wave w -> g-tile g0 = w*16 (8 MFMAs) ----
  {
    int g0 = w * 16;
    f32x4 acc = {0.f, 0.f, 0.f, 0.f};
#pragma unroll
    for (int kk = 0; kk < 8; kk++) {
      s16x8 a = *(const s16x8*)(Ib + lr * 264 + kk * 32 + lc * 8);
      s16x8 bfr = *(const s16x8*)(Wobf + (size_t)(g0 + lr) * 256 + kk * 32 + lc * 8);
      acc = __builtin_amdgcn_mfma_f32_16x16x32_bf16(a, bfr, acc, 0, 0, 0);
    }
    if ((lc >> 1) == (soff >> 3)) {     // rows we own
#pragma unroll
      for (int q = 0; q < 4; q++) {
        int rloc = (4 * lc + q) & 7;
        float val = acc[q] + bov;
        o_out[(size_t)(b * 128 + n0 + rloc) * 256 + g0 + lr] = val;
        outb[rloc * 260 + g0 + lr] = val;
      }
    }
  }
  __syncthreads();

  // ---- phase K: skill logits. t = (rloc<<7)|(s<<3)|p, 8-way split-K ----
  {
    int rloc = t >> 7, s = (t >> 3) & 15, p = t & 7;
    int row = b * 128 + n0 + rloc;
    const float4* Ws4 = (const float4*)(Wsm + s * 384);
    const float4* lp4 = (const float4*)(agents_local + (size_t)row * 64);
    const float4* gp4 = (const float4*)(goals + (size_t)row * 64);
    float acc = 0.f;
#pragma unroll
    for (int i = 0; i < 12; i++) {
      int cc = p * 48 + i * 4;
      float4 c4;
      if (cc < 64)       c4 = lp4[cc >> 2];
      else if (cc < 128) c4 = gp4[(cc - 64) >> 2];
      else               c4 = *(const float4*)&outb[rloc * 260 + (cc - 128)];
      float4 w4 = Ws4[cc >> 2];
      acc = fmaf(w4.x, c4.x, fmaf(w4.y, c4.y, fmaf(w4.z, c4.z, fmaf(w4.w, c4.w, acc))));
    }
    acc += __shfl_xor(acc, 1);
    acc += __shfl_xor(acc, 2);
    acc += __shfl_xor(acc, 4);
    if (p == 0) o_logit[row * 16 + s] = acc + bs[s];
  }
}

extern "C" void kernel_launch(void* const* d_in, const int* in_sizes, int n_in,
                              void* d_out, int out_size, void* d_ws, size_t ws_size,
                              hipStream_t stream) {
  const float* goals        = (const float*)d_in[0];
  const float* agents       = (const float*)d_in[1];
  const float* agents_local = (const float*)d_in[2];
  const float* u1           = (const float*)d_in[3];
  const float* u2           = (const float*)d_in[4];
  const float* Wq = (const float*)d_in[5];
  const float* bq = (const float*)d_in[6];
  const float* Wk = (const float*)d_in[7];
  const float* bk = (const float*)d_in[8];
  const float* Wv = (const float*)d_in[9];
  const float* bv = (const float*)d_in[10];
  const float* Wo = (const float*)d_in[11];
  const float* bo = (const float*)d_in[12];
  const float* Wsm = (const float*)d_in[13];
  const float* bs  = (const float*)d_in[14];
  float* out = (float*)d_out;
  float* ws  = (float*)d_ws;

  proj_k<<<256, 512, 0, stream>>>(goals, agents, Wq, bq, Wk, bk, Wv, bv, Wo, ws);
  attn_k<<<256, 1024, 0, stream>>>(goals, agents_local, u1, u2, bo, Wsm, bs, ws, out);
}